// Round 8
// baseline (78.393 us; speedup 1.0000x reference)
//
#include <hip/hip_runtime.h>
#include <hip/hip_fp16.h>

// Radon3D loss on MI355X — project the DIFFERENCE volume (radon is linear).
// Geometry (D=H=W=64, 120 angles over [0,120] deg): L=91, pad top=left=13.
//   ix(i,j) = 45*c*linj + 32 + 45*s - s*i,  iy(i,j) = 45*s*linj + 32 - 45*c + c*i
// Coords shifted +1 (nonneg), clamped to [0,65]: out-of-support samples hit
// the zero border with zero weight == map_coordinates mode='constant' cval=0.
//
// Ladder: R8 x4 bundles -> 74.0us (best). R9/R11/R12 occupancy/pipeline
// bets null/regressed; R13 bank swizzle NULL (no systematic resonance).
// R14 (this round): QUAD CELL. One 16B cell holds ALL FOUR bilinear corners
// for 2 slices: cell(y,x) = [D(y,x)|D(y,x+1)|D(y+1,x)|D(y+1,x+1)] (x2 fp16
// slices packed per corner). One ds_read_b128 per sample (was 2), ~25 instr
// per sample (was ~37), canvas 70.8KB for 2 slices -> NSL=2, 480 blocks,
// and 2 blocks/CU is now VGPR-legal (body ~60 VGPR <= 85 @ 6 waves/SIMD;
// the cap that doomed R9/R12). LDS read COUNT per slice unchanged -> this
// probe discriminates: win => issue/latency-bound; null => scattered-gather
// throughput is the wall (roofline).
// Bit-exactness: corner values, lerp ops, and ascending-i fp16 chain order
// identical; slice split across blocks == R9's (absmax stayed 0.0).
#define DD 64
#define NA 120
#define NS 64
#define LL 91
#define PS 66                 // cell rows (y = 0..65)
#define PSTR 67               // cell stride per row (odd, row-decorrelated)
#define NCELL (PS * PSTR)     // 4422 cells * 16 B = 70.75 KB
#define NSL 2                 // slices per block
#define NANG 8                // angles per block
#define JT 96                 // j-lanes per angle (91 active)
#define NTHR (NANG * JT)      // 768 threads = 12 waves
#define NSP (NS / NSL)        // 32 slice groups
#define NAP (NA / NANG)       // 15 angle groups
#define NBLKS (NSP * NAP)     // 480 blocks -> 2 per CU (LDS 141.5KB, 24 waves)
#define BW 4                  // bundle width (samples per unrolled round)

static __device__ __forceinline__ __half2 u2h(unsigned int u) {
    union { unsigned int u; __half2 h; } v; v.u = u; return v.h;
}
static __device__ __forceinline__ unsigned int h2u(__half2 h) {
    union { __half2 h; unsigned int u; } v; v.h = h; return v.u;
}

__global__ __launch_bounds__(NTHR, 6) void radon_loss_kernel(
    const float* __restrict__ vout, const float* __restrict__ vgt,
    float* __restrict__ out)
{
    __shared__ uint4 C[NCELL];           // quad canvas, 70.75 KB
    __shared__ float wsum[NTHR / 64];

    const int bid = blockIdx.x;
    const int sp = bid / NAP;            // slice group 0..31
    const int ap = bid - sp * NAP;       // angle group 0..14
    const int s0 = sp * NSL;
    const int t = threadIdx.x;

    // 1) zero the quad canvas (all never-written corners must be 0)
    for (int idx = t; idx < NCELL; idx += NTHR)
        C[idx] = make_uint4(0u, 0u, 0u, 0u);
    __syncthreads();

    // 2) stage fp16 diffs of 2 slices. Pixel at canvas (r=d+1, xc=w+1)
    //    appears in 4 cells:
    //    cell(r,xc).x   (its (y,x) corner)      cell(r,xc-1).y   ((y,x+1))
    //    cell(r-1,xc).z ((y+1,x))               cell(r-1,xc-1).w ((y+1,x+1))
    for (int idx = t; idx < DD * DD; idx += NTHR) {
        const int d = idx >> 6, w = idx & 63;
        const int g = d * 4096 + s0 * 64 + w;
        const float d0 = vout[g]      - vgt[g];
        const float d1 = vout[g + 64] - vgt[g + 64];
        const unsigned int pk = h2u(__floats2half2_rn(d0, d1));
        const int base = (d + 1) * PSTR + (w + 1);
        C[base].x            = pk;
        C[base - 1].y        = pk;
        C[base - PSTR].z     = pk;
        C[base - PSTR - 1].w = pk;
    }
    __syncthreads();

    // 3) projection: thread = (angle slot, column j); clipped i-range per thread
    const int ja = t / JT;
    const int j  = t - ja * JT;
    const int a  = ap * NANG + ja;
    const float theta = (float)a * (float)(3.14159265358979323846 * 120.0 / 119.0 / 180.0);
    const float c = cosf(theta), sn = sinf(theta);

    float val = 0.f;
    if (j < LL) {
        const float linj = fmaf((float)j, 2.0f / 90.0f, -1.0f);
        // +1 shift: coords in [0,65] after clamp; canvas row/col 0 is border
        const float bx1 = fmaf(c,  linj, 1.0f) * 45.0f - 12.0f + 45.0f * sn;
        const float by1 = fmaf(sn, linj, 1.0f) * 45.0f - 12.0f - 45.0f * c;

        // ---- chord clipping: support is xs in [0,65] AND ys in [0,65] ----
        // xs(i) = bx1 - i*sn  (sn >= 0 for theta in [0,120] deg)
        // ys(i) = by1 + i*c
        float loB = 0.f, hiB = (float)(LL - 1);
        if (sn > 1e-6f) {
            const float inv = 1.0f / sn;
            loB = fmaxf(loB, (bx1 - 65.0f) * inv);
            hiB = fminf(hiB, bx1 * inv);
        } else if (bx1 < 0.0f || bx1 > 65.0f) {
            hiB = -2.0f;                 // ray entirely outside support
        }
        if (fabsf(c) > 1e-6f) {
            const float inv = 1.0f / c;
            const float t0 = (0.0f - by1) * inv;
            const float t1 = (65.0f - by1) * inv;
            loB = fmaxf(loB, fminf(t0, t1));
            hiB = fminf(hiB, fmaxf(t0, t1));
        } else if (by1 < 0.0f || by1 > 65.0f) {
            hiB = -2.0f;
        }
        const int i0 = max(0, (int)loB - 1);          // loB >= 0: trunc == floor
        const int i1 = min(LL - 1, (int)hiB + 1);     // hiB < 0 -> i1 < i0 -> skip
        const int n  = i1 - i0 + 1;                   // may be <= 0

        __half2 acc01 = __floats2half2_rn(0.f, 0.f);
        // x4 bundles; over-run past i1 is safe & bit-identical (clamped coords
        // land on zero cells with zero weight for ANY i).
        float fb = (float)i0;                         // exact fp32 counter
        for (int k = 0; k < n; k += BW, fb += (float)BW) {
            int   cia[BW];
            float wxv[BW], wyv[BW];
            #pragma unroll
            for (int u = 0; u < BW; ++u) {
                const float fi = fb + (float)u;
                const float xs = fminf(fmaxf(fmaf(-fi, sn, bx1), 0.0f), 65.0f);
                const float ys = fminf(fmaxf(fmaf( fi, c,  by1), 0.0f), 65.0f);
                const int ix = (int)xs;            // trunc == floor (nonneg)
                const int iy = (int)ys;
                wxv[u] = xs - (float)ix;
                wyv[u] = ys - (float)iy;
                cia[u] = iy * PSTR + ix;
            }
            uint4 q[BW];
            #pragma unroll
            for (int u = 0; u < BW; ++u)
                q[u] = C[cia[u]];                  // ALL 4 corners, 2 slices
            #pragma unroll
            for (int u = 0; u < BW; ++u) {
                const __half2 wx2 = __float2half2_rn(wxv[u]);
                const __half2 wy2 = __float2half2_rn(wyv[u]);
                const __half2 t01 = __hfma2(wx2, __hsub2(u2h(q[u].y), u2h(q[u].x)), u2h(q[u].x));
                const __half2 b01 = __hfma2(wx2, __hsub2(u2h(q[u].w), u2h(q[u].z)), u2h(q[u].z));
                acc01 = __hadd2(acc01, __hfma2(wy2, __hsub2(b01, t01), t01));
            }
        }
        const float2 a01 = __half22float2(acc01);
        val = fabsf(a01.x) + fabsf(a01.y);
    }

    // 4) block reduction + one scaled atomic per block
    #pragma unroll
    for (int off = 32; off > 0; off >>= 1)
        val += __shfl_down(val, off);
    const int wave = t >> 6, lane = t & 63;
    if (lane == 0) wsum[wave] = val;
    __syncthreads();
    if (t == 0) {
        float v = 0.f;
        #pragma unroll
        for (int wv = 0; wv < NTHR / 64; ++wv) v += wsum[wv];
        atomicAdd(out, v * (1.0f / (float)(NA * LL)));
    }
}

extern "C" void kernel_launch(void* const* d_in, const int* in_sizes, int n_in,
                              void* d_out, int out_size, void* d_ws, size_t ws_size,
                              hipStream_t stream) {
    const float* vout = (const float*)d_in[0];
    const float* vgt  = (const float*)d_in[1];
    float* out = (float*)d_out;

    hipMemsetAsync(out, 0, sizeof(float), stream);
    radon_loss_kernel<<<NBLKS, NTHR, 0, stream>>>(vout, vgt, out);
}

// Round 9
// 73.303 us; speedup vs baseline: 1.0694x; 1.0694x over previous
//
#include <hip/hip_runtime.h>
#include <hip/hip_fp16.h>

// Radon3D loss on MI355X — project the DIFFERENCE volume (radon is linear).
// Geometry (D=H=W=64, 120 angles over [0,120] deg): L=91, pad top=left=13.
//   ix(i,j) = 45*c*linj + 32 + 45*s - s*i,  iy(i,j) = 45*s*linj + 32 - 45*c + c*i
// WIDE 16-byte canvas cells: [D(y,x) 4-slice fp16 | D(y,x+1) 4-slice fp16]
// -> all 16 bilinear corners in 2 x ds_read_b128.
// Coords shifted +1 (nonneg), clamped to [0,65]: out-of-support samples hit
// the zero border with zero weight == map_coordinates mode='constant' cval=0.
//
// Ledger: R8 x4 bundles 74.0us (BEST). R9/R12 occupancy regressed; R10 x8
// regressed; R11 SW-pipe null; R13 bank swizzle null; R14 quad-cell (half
// the LDS reads, 2 blocks/CU, MORE total instructions) regressed +4.4.
// => binding resource is per-wave INSTRUCTION ISSUE VOLUME.
// R15 (this round): CLAMP DIET. The min/max clamps are identity for all
// samples strictly inside the chord (by construction of loB/hiB). Split:
// clamped head (<=2) -> UNCLAMPED interior x4 bundles (exact fit, no
// overrun) -> clamped tail (<=5). Interior drops 4 VALU/sample (~13% of
// body) on ~93% of samples. Bit-exact: clamp-identity => same fmaf bits;
// ascending-i order kept; dropped overrun adds were exact zeros (only
// possible -0->+0, erased by final fabsf). absmax stays 0.0.
#define DD 64
#define NA 120
#define NS 64
#define LL 91
#define PS 67
#define PSTR 69               // cell stride per row
#define NCELL (PS * PSTR)     // 4623 cells * 16 B = 74.0 KB
#define NSL 4                 // slices per block
#define NANG 8                // angles per block
#define JT 96                 // j-lanes per angle (91 active)
#define NTHR (NANG * JT)      // 768 threads = 12 waves
#define NSP (NS / NSL)        // 16 slice groups
#define NAP (NA / NANG)       // 15 angle groups
#define NBLKS (NSP * NAP)     // 240 blocks -> 1 per CU, perfectly balanced
#define BW 4                  // bundle width (samples per unrolled round)

static __device__ __forceinline__ __half2 u2h(unsigned int u) {
    union { unsigned int u; __half2 h; } v; v.u = u; return v.h;
}
static __device__ __forceinline__ unsigned int h2u(__half2 h) {
    union { __half2 h; unsigned int u; } v; v.h = h; return v.u;
}

__global__ __launch_bounds__(NTHR) void radon_loss_kernel(
    const float* __restrict__ vout, const float* __restrict__ vgt,
    float* __restrict__ out)
{
    __shared__ uint4 C[NCELL];           // wide canvas, 74 KB
    __shared__ float wsum[NTHR / 64];

    const int bid = blockIdx.x;
    const int sp = bid / NAP;            // slice group 0..15
    const int ap = bid - sp * NAP;       // angle group 0..14
    const int s0 = sp * NSL;
    const int t = threadIdx.x;

    // 1) zero the padded wide canvas
    for (int idx = t; idx < NCELL; idx += NTHR)
        C[idx] = make_uint4(0u, 0u, 0u, 0u);
    __syncthreads();

    // 2) stage fp16 diffs of 4 slices. Pixel (d,w) -> 8 B pack, written to
    //    cell(d+1, w+1).lo (as "x" entry) and cell(d+1, w).hi (as "x+1" entry).
    for (int idx = t; idx < DD * DD; idx += NTHR) {
        const int d = idx >> 6, w = idx & 63;
        const int g = d * 4096 + s0 * 64 + w;
        const float d0 = vout[g]       - vgt[g];
        const float d1 = vout[g + 64]  - vgt[g + 64];
        const float d2 = vout[g + 128] - vgt[g + 128];
        const float d3 = vout[g + 192] - vgt[g + 192];
        uint2 v8;
        v8.x = h2u(__floats2half2_rn(d0, d1));
        v8.y = h2u(__floats2half2_rn(d2, d3));
        const int rb = (d + 1) * PSTR + w;
        ((uint2*)&C[rb + 1])[0] = v8;    // D(y, x=w+1), lo half
        ((uint2*)&C[rb])[1]     = v8;    // D(y, x=w)'s x+1 entry, hi half
    }
    __syncthreads();

    // 3) projection: thread = (angle slot, column j); clipped i-range per thread
    const int ja = t / JT;
    const int j  = t - ja * JT;
    const int a  = ap * NANG + ja;
    const float theta = (float)a * (float)(3.14159265358979323846 * 120.0 / 119.0 / 180.0);
    const float c = cosf(theta), sn = sinf(theta);

    float val = 0.f;
    if (j < LL) {
        const float linj = fmaf((float)j, 2.0f / 90.0f, -1.0f);
        // +1 shift: coords in [0,65] after clamp; canvas row/col 0 is border
        const float bx1 = fmaf(c,  linj, 1.0f) * 45.0f - 12.0f + 45.0f * sn;
        const float by1 = fmaf(sn, linj, 1.0f) * 45.0f - 12.0f - 45.0f * c;

        // ---- chord clipping: support is xs in [0,65] AND ys in [0,65] ----
        // xs(i) = bx1 - i*sn  (sn >= 0 for theta in [0,120] deg)
        // ys(i) = by1 + i*c
        float loB = 0.f, hiB = (float)(LL - 1);
        if (sn > 1e-6f) {
            const float inv = 1.0f / sn;
            loB = fmaxf(loB, (bx1 - 65.0f) * inv);
            hiB = fminf(hiB, bx1 * inv);
        } else if (bx1 < 0.0f || bx1 > 65.0f) {
            hiB = -2.0f;                 // ray entirely outside support
        }
        if (fabsf(c) > 1e-6f) {
            const float inv = 1.0f / c;
            const float t0 = (0.0f - by1) * inv;
            const float t1 = (65.0f - by1) * inv;
            loB = fmaxf(loB, fminf(t0, t1));
            hiB = fminf(hiB, fmaxf(t0, t1));
        } else if (by1 < 0.0f || by1 > 65.0f) {
            hiB = -2.0f;
        }
        const int i0 = max(0, (int)loB - 1);          // loB >= 0: trunc == floor
        const int i1 = min(LL - 1, (int)hiB + 1);     // hiB < 0 -> i1 < i0 -> skip
        const int n  = i1 - i0 + 1;                   // may be <= 0

        __half2 acc01 = __floats2half2_rn(0.f, 0.f);
        __half2 acc23 = acc01;

        // One clamped sample (identical numerics to the old loop body).
        #define SAMPLE_C(FI)                                                        \
        {                                                                           \
            const float xs = fminf(fmaxf(fmaf(-(FI), sn, bx1), 0.0f), 65.0f);       \
            const float ys = fminf(fmaxf(fmaf( (FI), c,  by1), 0.0f), 65.0f);       \
            const int ix = (int)xs;                                                 \
            const int iy = (int)ys;                                                 \
            const float wx = xs - (float)ix;                                        \
            const float wy = ys - (float)iy;                                        \
            const int ci = iy * PSTR + ix;                                          \
            const uint4 q0 = C[ci];                                                 \
            const uint4 q1 = C[ci + PSTR];                                          \
            const __half2 wx2 = __float2half2_rn(wx);                               \
            const __half2 wy2 = __float2half2_rn(wy);                               \
            const __half2 t01 = __hfma2(wx2, __hsub2(u2h(q0.z), u2h(q0.x)), u2h(q0.x)); \
            const __half2 b01 = __hfma2(wx2, __hsub2(u2h(q1.z), u2h(q1.x)), u2h(q1.x)); \
            acc01 = __hadd2(acc01, __hfma2(wy2, __hsub2(b01, t01), t01));           \
            const __half2 t23 = __hfma2(wx2, __hsub2(u2h(q0.w), u2h(q0.y)), u2h(q0.y)); \
            const __half2 b23 = __hfma2(wx2, __hsub2(u2h(q1.w), u2h(q1.y)), u2h(q1.y)); \
            acc23 = __hadd2(acc23, __hfma2(wy2, __hsub2(b23, t23), t23));           \
        }

        if (n > 0) {
            // clamped head: i0 .. min(i1, i0+1)  (<=2 samples)
            const int hend = min(i1, i0 + 1);
            for (int i = i0; i <= hend; ++i) SAMPLE_C((float)i);

            // unclamped interior: exact-fit x4 bundles starting at i0+2.
            // For i in [i0+2, i1-2], xs,ys in [0,65] by construction of
            // loB/hiB -> clamps are identity -> safe to omit.
            const int nb = (n > 4) ? ((n - 4) >> 2) : 0;
            float fb = (float)(i0 + 2);               // exact fp32 counter
            for (int b = 0; b < nb; ++b, fb += (float)BW) {
                int   cia[BW];
                float wxv[BW], wyv[BW];
                #pragma unroll
                for (int u = 0; u < BW; ++u) {
                    const float fi = fb + (float)u;
                    const float xs = fmaf(-fi, sn, bx1);   // in [0,65], no clamp
                    const float ys = fmaf( fi, c,  by1);   // in [0,65], no clamp
                    const int ix = (int)xs;            // trunc == floor (nonneg)
                    const int iy = (int)ys;
                    wxv[u] = xs - (float)ix;
                    wyv[u] = ys - (float)iy;
                    cia[u] = iy * PSTR + ix;
                }
                uint4 q0[BW], q1[BW];
                #pragma unroll
                for (int u = 0; u < BW; ++u) {
                    q0[u] = C[cia[u]];                 // row y  : [D(x) | D(x+1)]
                    q1[u] = C[cia[u] + PSTR];          // row y+1: [D(x) | D(x+1)]
                }
                #pragma unroll
                for (int u = 0; u < BW; ++u) {
                    const __half2 wx2 = __float2half2_rn(wxv[u]);
                    const __half2 wy2 = __float2half2_rn(wyv[u]);
                    // slices 0,1
                    const __half2 t01 = __hfma2(wx2, __hsub2(u2h(q0[u].z), u2h(q0[u].x)), u2h(q0[u].x));
                    const __half2 b01 = __hfma2(wx2, __hsub2(u2h(q1[u].z), u2h(q1[u].x)), u2h(q1[u].x));
                    acc01 = __hadd2(acc01, __hfma2(wy2, __hsub2(b01, t01), t01));
                    // slices 2,3
                    const __half2 t23 = __hfma2(wx2, __hsub2(u2h(q0[u].w), u2h(q0[u].y)), u2h(q0[u].y));
                    const __half2 b23 = __hfma2(wx2, __hsub2(u2h(q1[u].w), u2h(q1[u].y)), u2h(q1[u].y));
                    acc23 = __hadd2(acc23, __hfma2(wy2, __hsub2(b23, t23), t23));
                }
            }

            // clamped tail: i0+2+4*nb .. i1  (<=5 samples)
            for (int i = i0 + 2 + 4 * nb; i <= i1; ++i) SAMPLE_C((float)i);
        }
        #undef SAMPLE_C

        const float2 a01 = __half22float2(acc01);
        const float2 a23 = __half22float2(acc23);
        val = fabsf(a01.x) + fabsf(a01.y) + fabsf(a23.x) + fabsf(a23.y);
    }

    // 4) block reduction + one scaled atomic per block
    #pragma unroll
    for (int off = 32; off > 0; off >>= 1)
        val += __shfl_down(val, off);
    const int wave = t >> 6, lane = t & 63;
    if (lane == 0) wsum[wave] = val;
    __syncthreads();
    if (t == 0) {
        float v = 0.f;
        #pragma unroll
        for (int wv = 0; wv < NTHR / 64; ++wv) v += wsum[wv];
        atomicAdd(out, v * (1.0f / (float)(NA * LL)));
    }
}

extern "C" void kernel_launch(void* const* d_in, const int* in_sizes, int n_in,
                              void* d_out, int out_size, void* d_ws, size_t ws_size,
                              hipStream_t stream) {
    const float* vout = (const float*)d_in[0];
    const float* vgt  = (const float*)d_in[1];
    float* out = (float*)d_out;

    hipMemsetAsync(out, 0, sizeof(float), stream);
    radon_loss_kernel<<<NBLKS, NTHR, 0, stream>>>(vout, vgt, out);
}